// Round 6
// baseline (886.574 us; speedup 1.0000x reference)
//
#include <hip/hip_runtime.h>

#define NN 100000
#define EE 1600000

using bf16x8 = __attribute__((ext_vector_type(8))) short;
using f32x4  = __attribute__((ext_vector_type(4))) float;

static __device__ __forceinline__ unsigned short f2bh(float f) {
    unsigned int u = __float_as_uint(f);
    return (unsigned short)((u + 0x7FFFu + ((u >> 16) & 1u)) >> 16);
}
static __device__ __forceinline__ float bh2f(unsigned short h) {
    return __uint_as_float(((unsigned int)h) << 16);
}

// split 8 floats into hi/lo bf16x8 via truncation (residual exact in fp32)
static __device__ __forceinline__ void split_pack(float4 a, float4 b,
                                                  bf16x8& h, bf16x8& l) {
    float f[8] = {a.x, a.y, a.z, a.w, b.x, b.y, b.z, b.w};
    union { bf16x8 v; unsigned int u[4]; } H, L;
    #pragma unroll
    for (int e = 0; e < 4; ++e) {
        unsigned int u0 = __float_as_uint(f[2 * e]);
        unsigned int u1 = __float_as_uint(f[2 * e + 1]);
        H.u[e] = (u0 >> 16) | (u1 & 0xFFFF0000u);
        float r0 = f[2 * e]     - __uint_as_float(u0 & 0xFFFF0000u);
        float r1 = f[2 * e + 1] - __uint_as_float(u1 & 0xFFFF0000u);
        L.u[e] = (__float_as_uint(r0) >> 16) | (__float_as_uint(r1) & 0xFFFF0000u);
    }
    h = H.v; l = L.v;
}

// ---------------- degree count (no self loop; +1 applied in dinv) ----------
__global__ __launch_bounds__(256) void k_init(unsigned int* cnt) {
    int v = blockIdx.x * 256 + threadIdx.x;
    if (v < NN) cnt[v] = 0u;
}

__global__ __launch_bounds__(256) void k_count(const int* __restrict__ dst, unsigned int* cnt) {
    int e = blockIdx.x * 256 + threadIdx.x;
    if (e < EE) atomicAdd(&cnt[dst[e]], 1u);
}

__global__ __launch_bounds__(256) void k_dinv(const unsigned int* __restrict__ cnt, float* dinv) {
    int v = blockIdx.x * 256 + threadIdx.x;
    if (v < NN) dinv[v] = rsqrtf((float)(cnt[v] + 1u));
}

// ---------------- exclusive prefix scan (single workgroup, shfl-based) -----
__global__ __launch_bounds__(1024) void k_scan(const unsigned int* __restrict__ cnt,
        unsigned int* __restrict__ row_ptr, unsigned int* __restrict__ cursor) {
    __shared__ unsigned int wsum[16];
    __shared__ unsigned int carry_s;
    const int tid = threadIdx.x;
    const int lane = tid & 63, w = tid >> 6;
    if (tid == 0) carry_s = 0u;
    __syncthreads();
    for (int base = 0; base < NN; base += 1024) {
        int i = base + tid;
        unsigned int v = (i < NN) ? cnt[i] : 0u;
        unsigned int incl = v;
        #pragma unroll
        for (int off = 1; off < 64; off <<= 1) {
            unsigned int t = __shfl_up(incl, off, 64);
            if (lane >= off) incl += t;
        }
        if (lane == 63) wsum[w] = incl;
        __syncthreads();
        unsigned int woff = 0;
        #pragma unroll
        for (int j = 0; j < 16; ++j) woff += (j < w) ? wsum[j] : 0u;
        unsigned int c = carry_s;
        if (i < NN) {
            unsigned int excl = c + woff + incl - v;
            row_ptr[i] = excl;
            cursor[i] = excl;
        }
        __syncthreads();
        if (tid == 1023) carry_s = c + woff + incl;
        __syncthreads();
    }
}

// ---------------- CSR fill: csr_src grouped by dst ----------------
__global__ __launch_bounds__(256) void k_fill(const int* __restrict__ src,
        const int* __restrict__ dst, unsigned int* cursor, int* __restrict__ csr_src) {
    int e = blockIdx.x * 256 + threadIdx.x;
    if (e < EE) {
        int d = dst[e];
        unsigned int pos = atomicAdd(&cursor[d], 1u);
        csr_src[pos] = src[e];
    }
}

// ---------------- prep: Wg1 [1024][64] -> transposed split-bf16 [64][1024] --
__global__ __launch_bounds__(256) void k_prepW1(const float* __restrict__ W,
        unsigned short* __restrict__ wh, unsigned short* __restrict__ wl) {
    int t = blockIdx.x * 256 + threadIdx.x;       // 65536
    int k = t >> 6, c = t & 63;
    float f = W[k * 64 + c];
    unsigned short h = f2bh(f);
    wh[c * 1024 + k] = h;
    wl[c * 1024 + k] = f2bh(f - bh2f(h));
}

// ---------------- prep: Wf2 [64][1024] -> transposed split-bf16 [1024][64] --
__global__ __launch_bounds__(256) void k_prepW2(const float* __restrict__ W,
        unsigned short* __restrict__ wh, unsigned short* __restrict__ wl) {
    int t = blockIdx.x * 256 + threadIdx.x;       // 65536
    int k = t >> 10, c = t & 1023;
    float f = W[k * 1024 + c];
    unsigned short h = f2bh(f);
    wh[c * 64 + k] = h;
    wl[c * 64 + k] = f2bh(f - bh2f(h));
}

// ---------------- GEMM1 (streaming MFMA split-bf16) -------------------------
// No LDS, no barriers. 4 waves/block; wave = 32 rows x 64 cols.
// A: fp32 direct from global (coalesced, each element read once), split in reg.
// B: pre-split transposed tables, read from global (L2-hot, 256 KB total).
__global__ __launch_bounds__(256) void k_gemm1(const float* __restrict__ x,
        const unsigned short* __restrict__ wg1h, const unsigned short* __restrict__ wg1l,
        const float* __restrict__ dinv, float* __restrict__ g1) {
    const int tid = threadIdx.x;
    const int lane = tid & 63, w = tid >> 6;
    const int l16 = lane & 15, g = lane >> 4;
    const int row0 = blockIdx.x * 128 + w * 32;
    const int rA0 = row0 + l16, rA1 = row0 + 16 + l16;
    const float* xp0 = x + (size_t)rA0 * 1024;
    const float* xp1 = x + (size_t)rA1 * 1024;
    const bool ok0 = rA0 < NN, ok1 = rA1 < NN;
    const unsigned short* bh_base = wg1h + (size_t)l16 * 1024;
    const unsigned short* bl_base = wg1l + (size_t)l16 * 1024;
    f32x4 acc[2][4] = {};
    for (int kc = 0; kc < 1024; kc += 64) {
        #pragma unroll
        for (int ks = 0; ks < 64; ks += 32) {
            const int k0 = kc + ks + g * 8;
            float4 f00 = make_float4(0.f, 0.f, 0.f, 0.f), f01 = f00, f10 = f00, f11 = f00;
            if (ok0) { f00 = *(const float4*)(xp0 + k0); f01 = *(const float4*)(xp0 + k0 + 4); }
            if (ok1) { f10 = *(const float4*)(xp1 + k0); f11 = *(const float4*)(xp1 + k0 + 4); }
            bf16x8 ah0, al0, ah1, al1;
            split_pack(f00, f01, ah0, al0);
            split_pack(f10, f11, ah1, al1);
            #pragma unroll
            for (int nf = 0; nf < 4; ++nf) {
                const size_t boff = (size_t)nf * 16384 + k0;
                bf16x8 bh = *(const bf16x8*)(bh_base + boff);
                bf16x8 bl = *(const bf16x8*)(bl_base + boff);
                acc[0][nf] = __builtin_amdgcn_mfma_f32_16x16x32_bf16(ah0, bh, acc[0][nf], 0, 0, 0);
                acc[1][nf] = __builtin_amdgcn_mfma_f32_16x16x32_bf16(ah1, bh, acc[1][nf], 0, 0, 0);
                acc[0][nf] = __builtin_amdgcn_mfma_f32_16x16x32_bf16(al0, bh, acc[0][nf], 0, 0, 0);
                acc[1][nf] = __builtin_amdgcn_mfma_f32_16x16x32_bf16(al1, bh, acc[1][nf], 0, 0, 0);
                acc[0][nf] = __builtin_amdgcn_mfma_f32_16x16x32_bf16(ah0, bl, acc[0][nf], 0, 0, 0);
                acc[1][nf] = __builtin_amdgcn_mfma_f32_16x16x32_bf16(ah1, bl, acc[1][nf], 0, 0, 0);
            }
        }
    }
    #pragma unroll
    for (int mf = 0; mf < 2; ++mf) {
        #pragma unroll
        for (int r = 0; r < 4; ++r) {
            int node = row0 + mf * 16 + g * 4 + r;
            if (node < NN) {
                float di = dinv[node];
                #pragma unroll
                for (int nf = 0; nf < 4; ++nf)
                    g1[(size_t)node * 64 + nf * 16 + l16] = acc[mf][nf][r] * di;
            }
        }
    }
}

// ------- gather 64ch + fused norm/bias/relu ---------------------------------
__global__ __launch_bounds__(256) void k_gather64(const float* __restrict__ g1,
        const int* __restrict__ csr, const unsigned int* __restrict__ row_ptr,
        const unsigned int* __restrict__ cnt, const float* __restrict__ dinv,
        const float* __restrict__ bg1, float* __restrict__ h) {
    int wv = (blockIdx.x * 256 + threadIdx.x) >> 6;   // wave = node
    int lane = threadIdx.x & 63;
    if (wv >= NN) return;
    unsigned int s0 = row_ptr[wv];
    unsigned int n = cnt[wv];
    float sum = g1[(size_t)wv * 64 + lane];           // self loop
    unsigned int i = s0, end = s0 + n;
    for (; i + 2 <= end; i += 2) {
        int a = csr[i], b = csr[i + 1];
        float va = g1[(size_t)a * 64 + lane];
        float vb = g1[(size_t)b * 64 + lane];
        sum += va + vb;
    }
    if (i < end) sum += g1[(size_t)csr[i] * 64 + lane];
    h[(size_t)wv * 64 + lane] = fmaxf(sum * dinv[wv] + bg1[lane], 0.f);
}

// ---------------- layer2 GEMM (fp32, tiny): g2 = (h @ Wg2) * dinv[row] ------
__global__ __launch_bounds__(256) void k_layer2(const float* __restrict__ h,
        const float* __restrict__ Wg2, const float* __restrict__ dinv,
        float* __restrict__ g2) {
    __shared__ __align__(16) float as[64][68];
    __shared__ __align__(16) float wsh[64][32];
    const int tid = threadIdx.x;
    const int node0 = blockIdx.x * 64;
    {
        const int lr = tid >> 4, lk = (tid & 15) * 4;
        #pragma unroll
        for (int l = 0; l < 4; ++l) {
            int r = lr + l * 16, v = node0 + r;
            float4 a = make_float4(0.f, 0.f, 0.f, 0.f);
            if (v < NN) a = *(const float4*)(h + (size_t)v * 64 + lk);
            *(float4*)&as[r][lk] = a;
        }
        const int wr = tid >> 3, wk = (tid & 7) * 4;
        #pragma unroll
        for (int l = 0; l < 2; ++l) {
            int r = wr + l * 32;
            *(float4*)&wsh[r][wk] = *(const float4*)(Wg2 + (size_t)r * 32 + wk);
        }
    }
    __syncthreads();
    const int tx = tid & 7, ty = tid >> 3;
    float acc[2][4] = {{0.f}};
    for (int kk = 0; kk < 64; kk += 4) {
        float wv[4][4];
        #pragma unroll
        for (int j = 0; j < 4; ++j)
            *(float4*)&wv[j][0] = *(const float4*)&wsh[kk + j][tx * 4];
        #pragma unroll
        for (int i = 0; i < 2; ++i) {
            float xv[4];
            *(float4*)&xv[0] = *(const float4*)&as[ty * 2 + i][kk];
            #pragma unroll
            for (int j = 0; j < 4; ++j) {
                #pragma unroll
                for (int c = 0; c < 4; ++c)
                    acc[i][c] += xv[j] * wv[j][c];
            }
        }
    }
    #pragma unroll
    for (int i = 0; i < 2; ++i) {
        int v = node0 + ty * 2 + i;
        if (v < NN) {
            float di = dinv[v];
            float4 o;
            o.x = acc[i][0] * di; o.y = acc[i][1] * di;
            o.z = acc[i][2] * di; o.w = acc[i][3] * di;
            *(float4*)(g2 + (size_t)v * 32 + tx * 4) = o;
        }
    }
}

// ------- gather 32ch + fused norm/bias --------------------------------------
__global__ __launch_bounds__(256) void k_gather32(const float* __restrict__ g2,
        const int* __restrict__ csr, const unsigned int* __restrict__ row_ptr,
        const unsigned int* __restrict__ cnt, const float* __restrict__ dinv,
        const float* __restrict__ bg2, float* __restrict__ z) {
    int node = (blockIdx.x * 256 + threadIdx.x) >> 5;  // half-wave = node
    int c = threadIdx.x & 31;
    if (node >= NN) return;
    unsigned int s0 = row_ptr[node];
    unsigned int n = cnt[node];
    float sum = g2[(size_t)node * 32 + c];
    unsigned int i = s0, end = s0 + n;
    for (; i + 2 <= end; i += 2) {
        int a = csr[i], b = csr[i + 1];
        float va = g2[(size_t)a * 32 + c];
        float vb = g2[(size_t)b * 32 + c];
        sum += va + vb;
    }
    if (i < end) sum += g2[(size_t)csr[i] * 32 + c];
    z[(size_t)node * 32 + c] = sum * dinv[node] + bg2[c];
}

// ---------------- decode (MFMA): 64 nodes x full 1024 cols per block --------
__global__ __launch_bounds__(256) void k_decode(const float* __restrict__ z,
        const float* __restrict__ Wf1, const float* __restrict__ bf1,
        const unsigned short* __restrict__ w2hg, const unsigned short* __restrict__ w2lg,
        const float* __restrict__ bf2, float* __restrict__ out) {
    __shared__ __align__(16) unsigned char smem[36864];
    float (*dsh)[68] = (float (*)[68])smem;                          // 64x68 f
    float (*zs)[36]  = (float (*)[36])(smem + 17408);                // 64x36 f
    float (*w1s)[64] = (float (*)[64])(smem + 17408 + 9216);         // 32x64 f
    unsigned short (*w2h)[72] = (unsigned short (*)[72])smem;        // 128x72 u16
    unsigned short (*w2l)[72] = (unsigned short (*)[72])(smem + 18432);
    const int tid = threadIdx.x;
    const int lane = tid & 63, w = tid >> 6;
    const int l16 = lane & 15, g = lane >> 4;
    const int node0 = blockIdx.x * 64;

    // phase 1a: stage z [64][32] and Wf1 [32][64]
    #pragma unroll
    for (int j = 0; j < 2; ++j) {
        int fi = tid + 256 * j;
        int v = fi >> 3, m4 = (fi & 7) * 4;
        float4 zz = make_float4(0.f, 0.f, 0.f, 0.f);
        if (node0 + v < NN) zz = *(const float4*)(z + (size_t)(node0 + v) * 32 + m4);
        *(float4*)&zs[v][m4] = zz;
    }
    #pragma unroll
    for (int j = 0; j < 2; ++j) {
        int fi = tid + 256 * j;
        int r = fi >> 4, c4 = (fi & 15) * 4;
        *(float4*)&w1s[r][c4] = *(const float4*)(Wf1 + (size_t)r * 64 + c4);
    }
    __syncthreads();

    // phase 1b: d = relu(z @ Wf1 + bf1) -> dsh (fp32)
    {
        const int dtx = tid & 15, dty = tid >> 4;
        float acc[4][4] = {{0.f}};
        for (int m = 0; m < 32; m += 4) {
            float wv[4][4];
            #pragma unroll
            for (int j = 0; j < 4; ++j)
                *(float4*)&wv[j][0] = *(const float4*)&w1s[m + j][dtx * 4];
            #pragma unroll
            for (int i = 0; i < 4; ++i) {
                float zv[4];
                *(float4*)&zv[0] = *(const float4*)&zs[dty * 4 + i][m];
                #pragma unroll
                for (int j = 0; j < 4; ++j) {
                    #pragma unroll
                    for (int c = 0; c < 4; ++c)
                        acc[i][c] += zv[j] * wv[j][c];
                }
            }
        }
        float4 b4 = *(const float4*)(bf1 + dtx * 4);
        #pragma unroll
        for (int i = 0; i < 4; ++i) {
            float4 dd;
            dd.x = fmaxf(acc[i][0] + b4.x, 0.f);
            dd.y = fmaxf(acc[i][1] + b4.y, 0.f);
            dd.z = fmaxf(acc[i][2] + b4.z, 0.f);
            dd.w = fmaxf(acc[i][3] + b4.w, 0.f);
            *(float4*)&dsh[dty * 4 + i][dtx * 4] = dd;
        }
    }
    __syncthreads();

    // phase 2: per-wave A-frags in registers (16 nodes/wave, split-bf16)
    bf16x8 ah[2], al[2];
    {
        int row = w * 16 + l16;
        #pragma unroll
        for (int s = 0; s < 2; ++s) {
            int k0 = s * 32 + g * 8;
            float4 f0 = *(float4*)&dsh[row][k0];
            float4 f1 = *(float4*)&dsh[row][k0 + 4];
            float fv[8] = {f0.x, f0.y, f0.z, f0.w, f1.x, f1.y, f1.z, f1.w};
            bf16x8 hv, lv;
            #pragma unroll
            for (int e = 0; e < 8; ++e) {
                unsigned short hh = f2bh(fv[e]);
                hv[e] = (short)hh;
                lv[e] = (short)f2bh(fv[e] - bh2f(hh));
            }
            ah[s] = hv; al[s] = lv;
        }
    }
    __syncthreads();   // dsh dead; w2 may now overwrite

    // phase 3: col chunks of 128
    for (int ch = 0; ch < 8; ++ch) {
        const int col0 = ch * 128;
        #pragma unroll
        for (int j = 0; j < 4; ++j) {
            int fi = tid + 256 * j;
            int c = fi >> 3, k8 = (fi & 7) * 8;
            *(uint4*)&w2h[c][k8] = *(const uint4*)(w2hg + (size_t)(col0 + c) * 64 + k8);
            *(uint4*)&w2l[c][k8] = *(const uint4*)(w2lg + (size_t)(col0 + c) * 64 + k8);
        }
        __syncthreads();
        f32x4 acc[8] = {};
        #pragma unroll
        for (int nf = 0; nf < 8; ++nf) {
            int c = nf * 16 + l16;
            #pragma unroll
            for (int s = 0; s < 2; ++s) {
                int k0 = s * 32 + g * 8;
                bf16x8 bh = *(const bf16x8*)&w2h[c][k0];
                bf16x8 bl = *(const bf16x8*)&w2l[c][k0];
                acc[nf] = __builtin_amdgcn_mfma_f32_16x16x32_bf16(ah[s], bh, acc[nf], 0, 0, 0);
                acc[nf] = __builtin_amdgcn_mfma_f32_16x16x32_bf16(al[s], bh, acc[nf], 0, 0, 0);
                acc[nf] = __builtin_amdgcn_mfma_f32_16x16x32_bf16(ah[s], bl, acc[nf], 0, 0, 0);
            }
        }
        #pragma unroll
        for (int nf = 0; nf < 8; ++nf) {
            int col = col0 + nf * 16 + l16;
            float b = bf2[col];
            #pragma unroll
            for (int r = 0; r < 4; ++r) {
                int node = node0 + w * 16 + g * 4 + r;
                if (node < NN)
                    out[(size_t)node * 1024 + col] = fmaxf(acc[nf][r] + b, 0.f);
            }
        }
        __syncthreads();
    }
}

extern "C" void kernel_launch(void* const* d_in, const int* in_sizes, int n_in,
                              void* d_out, int out_size, void* d_ws, size_t ws_size,
                              hipStream_t stream) {
    const float* x   = (const float*)d_in[0];
    const int* ei    = (const int*)d_in[1];
    const float* Wg1 = (const float*)d_in[2];
    const float* bg1 = (const float*)d_in[3];
    const float* Wg2 = (const float*)d_in[4];
    const float* bg2 = (const float*)d_in[5];
    const float* Wf1 = (const float*)d_in[6];
    const float* bf1 = (const float*)d_in[7];
    const float* Wf2 = (const float*)d_in[8];
    const float* bf2 = (const float*)d_in[9];
    float* out = (float*)d_out;
    float* ws  = (float*)d_ws;

    const int* src = ei;
    const int* dst = ei + EE;

    // ws (26 MB): dinv | g2 | z ; Wf2T tables overlay g2 after k_gather32.
    float* dinv = ws;
    float* g2   = ws + NN;
    float* z    = ws + NN + 32 * NN;
    unsigned short* wf2h = (unsigned short*)g2;            // 64K u16
    unsigned short* wf2l = wf2h + 64 * 1024;               // 64K u16

    // d_out scratch (all dead before k_decode writes out):
    float* g1 = out;                                       // 64N floats
    float* h  = out + (size_t)64 * NN;                     // 64N floats
    unsigned short* wg1h = (unsigned short*)h;             // 64K u16 (dead
    unsigned short* wg1l = wg1h + 64 * 1024;               //  before h write)
    int*      csr_src = (int*)(out + (size_t)128 * NN);    // E ints
    unsigned int* cnt     = (unsigned int*)(csr_src + EE); // N
    unsigned int* row_ptr = cnt + NN;                      // N
    unsigned int* cursor  = row_ptr + NN;                  // N

    k_init  <<<(NN + 255) / 256, 256, 0, stream>>>(cnt);
    k_count <<<(EE + 255) / 256, 256, 0, stream>>>(dst, cnt);
    k_dinv  <<<(NN + 255) / 256, 256, 0, stream>>>(cnt, dinv);
    k_scan  <<<1, 1024, 0, stream>>>(cnt, row_ptr, cursor);
    k_fill  <<<(EE + 255) / 256, 256, 0, stream>>>(src, dst, cursor, csr_src);
    k_prepW1<<<256, 256, 0, stream>>>(Wg1, wg1h, wg1l);
    k_gemm1 <<<(NN + 127) / 128, 256, 0, stream>>>(x, wg1h, wg1l, dinv, g1);
    k_gather64<<<(NN * 64 + 255) / 256, 256, 0, stream>>>(g1, csr_src, row_ptr, cnt, dinv, bg1, h);
    k_layer2<<<(NN + 63) / 64, 256, 0, stream>>>(h, Wg2, dinv, g2);
    k_gather32<<<(NN * 32 + 255) / 256, 256, 0, stream>>>(g2, csr_src, row_ptr, cnt, dinv, bg2, z);
    k_prepW2<<<256, 256, 0, stream>>>(Wf2, wf2h, wf2l);
    k_decode<<<(NN + 63) / 64, 256, 0, stream>>>(z, Wf1, bf1, wf2h, wf2l, bf2, out);
}

// Round 7
// 789.544 us; speedup vs baseline: 1.1229x; 1.1229x over previous
//
#include <hip/hip_runtime.h>

#define NN 100000
#define EE 1600000

using bf16x8 = __attribute__((ext_vector_type(8))) short;
using f32x4  = __attribute__((ext_vector_type(4))) float;

static __device__ __forceinline__ unsigned short f2bh(float f) {
    unsigned int u = __float_as_uint(f);
    return (unsigned short)((u + 0x7FFFu + ((u >> 16) & 1u)) >> 16);
}
static __device__ __forceinline__ float bh2f(unsigned short h) {
    return __uint_as_float(((unsigned int)h) << 16);
}

// split 8 floats into hi/lo bf16x8 via truncation (residual exact in fp32)
static __device__ __forceinline__ void split_pack(float4 a, float4 b,
                                                  bf16x8& h, bf16x8& l) {
    float f[8] = {a.x, a.y, a.z, a.w, b.x, b.y, b.z, b.w};
    union { bf16x8 v; unsigned int u[4]; } H, L;
    #pragma unroll
    for (int e = 0; e < 4; ++e) {
        unsigned int u0 = __float_as_uint(f[2 * e]);
        unsigned int u1 = __float_as_uint(f[2 * e + 1]);
        H.u[e] = (u0 >> 16) | (u1 & 0xFFFF0000u);
        float r0 = f[2 * e]     - __uint_as_float(u0 & 0xFFFF0000u);
        float r1 = f[2 * e + 1] - __uint_as_float(u1 & 0xFFFF0000u);
        L.u[e] = (__float_as_uint(r0) >> 16) | (__float_as_uint(r1) & 0xFFFF0000u);
    }
    h = H.v; l = L.v;
}

// ---------------- degree count (no self loop; +1 applied in dinv) ----------
__global__ __launch_bounds__(256) void k_init(unsigned int* cnt) {
    int v = blockIdx.x * 256 + threadIdx.x;
    if (v < NN) cnt[v] = 0u;
}

__global__ __launch_bounds__(256) void k_count(const int* __restrict__ dst, unsigned int* cnt) {
    int e = blockIdx.x * 256 + threadIdx.x;
    if (e < EE) atomicAdd(&cnt[dst[e]], 1u);
}

__global__ __launch_bounds__(256) void k_dinv(const unsigned int* __restrict__ cnt, float* dinv) {
    int v = blockIdx.x * 256 + threadIdx.x;
    if (v < NN) dinv[v] = rsqrtf((float)(cnt[v] + 1u));
}

// ---------------- exclusive prefix scan (single workgroup, shfl-based) -----
__global__ __launch_bounds__(1024) void k_scan(const unsigned int* __restrict__ cnt,
        unsigned int* __restrict__ row_ptr, unsigned int* __restrict__ cursor) {
    __shared__ unsigned int wsum[16];
    __shared__ unsigned int carry_s;
    const int tid = threadIdx.x;
    const int lane = tid & 63, w = tid >> 6;
    if (tid == 0) carry_s = 0u;
    __syncthreads();
    for (int base = 0; base < NN; base += 1024) {
        int i = base + tid;
        unsigned int v = (i < NN) ? cnt[i] : 0u;
        unsigned int incl = v;
        #pragma unroll
        for (int off = 1; off < 64; off <<= 1) {
            unsigned int t = __shfl_up(incl, off, 64);
            if (lane >= off) incl += t;
        }
        if (lane == 63) wsum[w] = incl;
        __syncthreads();
        unsigned int woff = 0;
        #pragma unroll
        for (int j = 0; j < 16; ++j) woff += (j < w) ? wsum[j] : 0u;
        unsigned int c = carry_s;
        if (i < NN) {
            unsigned int excl = c + woff + incl - v;
            row_ptr[i] = excl;
            cursor[i] = excl;
        }
        __syncthreads();
        if (tid == 1023) carry_s = c + woff + incl;
        __syncthreads();
    }
}

// ---------------- CSR fill: csr_src grouped by dst ----------------
__global__ __launch_bounds__(256) void k_fill(const int* __restrict__ src,
        const int* __restrict__ dst, unsigned int* cursor, int* __restrict__ csr_src) {
    int e = blockIdx.x * 256 + threadIdx.x;
    if (e < EE) {
        int d = dst[e];
        unsigned int pos = atomicAdd(&cursor[d], 1u);
        csr_src[pos] = src[e];
    }
}

// ------- prep: Wg1 [1024][64] -> chunked LDS image [16][2][64][72] u16 ------
// chunk = k/64; table 0 = hi, 1 = lo; pad cols 64..71 unused.
__global__ __launch_bounds__(256) void k_prepW1(const float* __restrict__ W,
        unsigned short* __restrict__ img) {
    int t = blockIdx.x * 256 + threadIdx.x;       // 65536
    int k = t >> 6, c = t & 63;
    float f = W[k * 64 + c];
    unsigned short h = f2bh(f);
    size_t base = (size_t)(k >> 6) * 9216 + (size_t)c * 72 + (k & 63);
    img[base] = h;
    img[base + 4608] = f2bh(f - bh2f(h));
}

// ---------------- prep: Wf2 [64][1024] -> transposed split-bf16 [1024][64] --
__global__ __launch_bounds__(256) void k_prepW2(const float* __restrict__ W,
        unsigned short* __restrict__ wh, unsigned short* __restrict__ wl) {
    int t = blockIdx.x * 256 + threadIdx.x;       // 65536
    int k = t >> 10, c = t & 1023;
    float f = W[k * 1024 + c];
    unsigned short h = f2bh(f);
    wh[c * 64 + k] = h;
    wl[c * 64 + k] = f2bh(f - bh2f(h));
}

// ---------------- GEMM1 v3: A streamed, B LDS double-buffered ---------------
// 4 waves/block; wave = 16 rows x 64 cols; block = 64 rows. Grid 1563.
// B staged per 64-K chunk via global_load_lds (async, overlapped with MFMA).
__global__ __launch_bounds__(256) void k_gemm1(const float* __restrict__ x,
        const unsigned short* __restrict__ wimg,
        const float* __restrict__ dinv, float* __restrict__ g1) {
    __shared__ __align__(16) unsigned short bs[2][2][64][72];   // 36864 B
    const int tid = threadIdx.x;
    const int lane = tid & 63, w = tid >> 6;
    const int l16 = lane & 15, g = lane >> 4;
    const int row0 = blockIdx.x * 64 + w * 16;
    const int rA = row0 + l16;
    const bool okA = rA < NN;
    const float* xp = x + (size_t)rA * 1024;
    f32x4 acc[4] = {};
    // prologue: stage chunk 0 into buf 0
    {
        const char* gb = (const char*)wimg;
        char* lb = (char*)&bs[0][0][0][0];
        for (int j = w; j < 18; j += 4)
            __builtin_amdgcn_global_load_lds((const unsigned int*)(gb + j * 1024 + lane * 16),
                                             (unsigned int*)(lb + j * 1024), 16, 0, 0);
    }
    __syncthreads();
    int cur = 0;
    for (int t = 0; t < 16; ++t) {
        if (t < 15) {                     // async stage next chunk into other buf
            const char* gb = (const char*)wimg + (size_t)(t + 1) * 18432;
            char* lb = (char*)&bs[cur ^ 1][0][0][0];
            for (int j = w; j < 18; j += 4)
                __builtin_amdgcn_global_load_lds((const unsigned int*)(gb + j * 1024 + lane * 16),
                                                 (unsigned int*)(lb + j * 1024), 16, 0, 0);
        }
        const int kc = t * 64;
        #pragma unroll
        for (int ks = 0; ks < 64; ks += 32) {
            const int k0 = kc + ks + g * 8;
            float4 f0 = make_float4(0.f, 0.f, 0.f, 0.f), f1 = f0;
            if (okA) { f0 = *(const float4*)(xp + k0); f1 = *(const float4*)(xp + k0 + 4); }
            bf16x8 ah, al;
            split_pack(f0, f1, ah, al);
            const int kk8 = (ks >> 3) + g;        // 0..7 within chunk
            #pragma unroll
            for (int nf = 0; nf < 4; ++nf) {
                bf16x8 bh = *(const bf16x8*)&bs[cur][0][nf * 16 + l16][kk8 * 8];
                bf16x8 bl = *(const bf16x8*)&bs[cur][1][nf * 16 + l16][kk8 * 8];
                acc[nf] = __builtin_amdgcn_mfma_f32_16x16x32_bf16(ah, bh, acc[nf], 0, 0, 0);
                acc[nf] = __builtin_amdgcn_mfma_f32_16x16x32_bf16(al, bh, acc[nf], 0, 0, 0);
                acc[nf] = __builtin_amdgcn_mfma_f32_16x16x32_bf16(ah, bl, acc[nf], 0, 0, 0);
            }
        }
        __syncthreads();                  // drains staging vmem; buffers swap safe
        cur ^= 1;
    }
    #pragma unroll
    for (int r = 0; r < 4; ++r) {
        int node = row0 + g * 4 + r;
        if (node < NN) {
            float di = dinv[node];
            #pragma unroll
            for (int nf = 0; nf < 4; ++nf)
                g1[(size_t)node * 64 + nf * 16 + l16] = acc[nf][r] * di;
        }
    }
}

// ------- gather 64ch + fused norm/bias/relu ---------------------------------
__global__ __launch_bounds__(256) void k_gather64(const float* __restrict__ g1,
        const int* __restrict__ csr, const unsigned int* __restrict__ row_ptr,
        const unsigned int* __restrict__ cnt, const float* __restrict__ dinv,
        const float* __restrict__ bg1, float* __restrict__ h) {
    int wv = (blockIdx.x * 256 + threadIdx.x) >> 6;   // wave = node
    int lane = threadIdx.x & 63;
    if (wv >= NN) return;
    unsigned int s0 = row_ptr[wv];
    unsigned int n = cnt[wv];
    float sum = g1[(size_t)wv * 64 + lane];           // self loop
    unsigned int i = s0, end = s0 + n;
    for (; i + 2 <= end; i += 2) {
        int a = csr[i], b = csr[i + 1];
        float va = g1[(size_t)a * 64 + lane];
        float vb = g1[(size_t)b * 64 + lane];
        sum += va + vb;
    }
    if (i < end) sum += g1[(size_t)csr[i] * 64 + lane];
    h[(size_t)wv * 64 + lane] = fmaxf(sum * dinv[wv] + bg1[lane], 0.f);
}

// ---------------- layer2 GEMM (fp32, tiny): g2 = (h @ Wg2) * dinv[row] ------
__global__ __launch_bounds__(256) void k_layer2(const float* __restrict__ h,
        const float* __restrict__ Wg2, const float* __restrict__ dinv,
        float* __restrict__ g2) {
    __shared__ __align__(16) float as[64][68];
    __shared__ __align__(16) float wsh[64][32];
    const int tid = threadIdx.x;
    const int node0 = blockIdx.x * 64;
    {
        const int lr = tid >> 4, lk = (tid & 15) * 4;
        #pragma unroll
        for (int l = 0; l < 4; ++l) {
            int r = lr + l * 16, v = node0 + r;
            float4 a = make_float4(0.f, 0.f, 0.f, 0.f);
            if (v < NN) a = *(const float4*)(h + (size_t)v * 64 + lk);
            *(float4*)&as[r][lk] = a;
        }
        const int wr = tid >> 3, wk = (tid & 7) * 4;
        #pragma unroll
        for (int l = 0; l < 2; ++l) {
            int r = wr + l * 32;
            *(float4*)&wsh[r][wk] = *(const float4*)(Wg2 + (size_t)r * 32 + wk);
        }
    }
    __syncthreads();
    const int tx = tid & 7, ty = tid >> 3;
    float acc[2][4] = {{0.f}};
    for (int kk = 0; kk < 64; kk += 4) {
        float wv[4][4];
        #pragma unroll
        for (int j = 0; j < 4; ++j)
            *(float4*)&wv[j][0] = *(const float4*)&wsh[kk + j][tx * 4];
        #pragma unroll
        for (int i = 0; i < 2; ++i) {
            float xv[4];
            *(float4*)&xv[0] = *(const float4*)&as[ty * 2 + i][kk];
            #pragma unroll
            for (int j = 0; j < 4; ++j) {
                #pragma unroll
                for (int c = 0; c < 4; ++c)
                    acc[i][c] += xv[j] * wv[j][c];
            }
        }
    }
    #pragma unroll
    for (int i = 0; i < 2; ++i) {
        int v = node0 + ty * 2 + i;
        if (v < NN) {
            float di = dinv[v];
            float4 o;
            o.x = acc[i][0] * di; o.y = acc[i][1] * di;
            o.z = acc[i][2] * di; o.w = acc[i][3] * di;
            *(float4*)(g2 + (size_t)v * 32 + tx * 4) = o;
        }
    }
}

// ------- gather 32ch + fused norm/bias --------------------------------------
__global__ __launch_bounds__(256) void k_gather32(const float* __restrict__ g2,
        const int* __restrict__ csr, const unsigned int* __restrict__ row_ptr,
        const unsigned int* __restrict__ cnt, const float* __restrict__ dinv,
        const float* __restrict__ bg2, float* __restrict__ z) {
    int node = (blockIdx.x * 256 + threadIdx.x) >> 5;  // half-wave = node
    int c = threadIdx.x & 31;
    if (node >= NN) return;
    unsigned int s0 = row_ptr[node];
    unsigned int n = cnt[node];
    float sum = g2[(size_t)node * 32 + c];
    unsigned int i = s0, end = s0 + n;
    for (; i + 2 <= end; i += 2) {
        int a = csr[i], b = csr[i + 1];
        float va = g2[(size_t)a * 32 + c];
        float vb = g2[(size_t)b * 32 + c];
        sum += va + vb;
    }
    if (i < end) sum += g2[(size_t)csr[i] * 32 + c];
    z[(size_t)node * 32 + c] = sum * dinv[node] + bg2[c];
}

// ---------------- decode (MFMA): 64 nodes x full 1024 cols per block --------
__global__ __launch_bounds__(256) void k_decode(const float* __restrict__ z,
        const float* __restrict__ Wf1, const float* __restrict__ bf1,
        const unsigned short* __restrict__ w2hg, const unsigned short* __restrict__ w2lg,
        const float* __restrict__ bf2, float* __restrict__ out) {
    __shared__ __align__(16) unsigned char smem[36864];
    float (*dsh)[68] = (float (*)[68])smem;                          // 64x68 f
    float (*zs)[36]  = (float (*)[36])(smem + 17408);                // 64x36 f
    float (*w1s)[64] = (float (*)[64])(smem + 17408 + 9216);         // 32x64 f
    unsigned short (*w2h)[72] = (unsigned short (*)[72])smem;        // 128x72 u16
    unsigned short (*w2l)[72] = (unsigned short (*)[72])(smem + 18432);
    const int tid = threadIdx.x;
    const int lane = tid & 63, w = tid >> 6;
    const int l16 = lane & 15, g = lane >> 4;
    const int node0 = blockIdx.x * 64;

    // phase 1a: stage z [64][32] and Wf1 [32][64]
    #pragma unroll
    for (int j = 0; j < 2; ++j) {
        int fi = tid + 256 * j;
        int v = fi >> 3, m4 = (fi & 7) * 4;
        float4 zz = make_float4(0.f, 0.f, 0.f, 0.f);
        if (node0 + v < NN) zz = *(const float4*)(z + (size_t)(node0 + v) * 32 + m4);
        *(float4*)&zs[v][m4] = zz;
    }
    #pragma unroll
    for (int j = 0; j < 2; ++j) {
        int fi = tid + 256 * j;
        int r = fi >> 4, c4 = (fi & 15) * 4;
        *(float4*)&w1s[r][c4] = *(const float4*)(Wf1 + (size_t)r * 64 + c4);
    }
    __syncthreads();

    // phase 1b: d = relu(z @ Wf1 + bf1) -> dsh (fp32)
    {
        const int dtx = tid & 15, dty = tid >> 4;
        float acc[4][4] = {{0.f}};
        for (int m = 0; m < 32; m += 4) {
            float wv[4][4];
            #pragma unroll
            for (int j = 0; j < 4; ++j)
                *(float4*)&wv[j][0] = *(const float4*)&w1s[m + j][dtx * 4];
            #pragma unroll
            for (int i = 0; i < 4; ++i) {
                float zv[4];
                *(float4*)&zv[0] = *(const float4*)&zs[dty * 4 + i][m];
                #pragma unroll
                for (int j = 0; j < 4; ++j) {
                    #pragma unroll
                    for (int c = 0; c < 4; ++c)
                        acc[i][c] += zv[j] * wv[j][c];
                }
            }
        }
        float4 b4 = *(const float4*)(bf1 + dtx * 4);
        #pragma unroll
        for (int i = 0; i < 4; ++i) {
            float4 dd;
            dd.x = fmaxf(acc[i][0] + b4.x, 0.f);
            dd.y = fmaxf(acc[i][1] + b4.y, 0.f);
            dd.z = fmaxf(acc[i][2] + b4.z, 0.f);
            dd.w = fmaxf(acc[i][3] + b4.w, 0.f);
            *(float4*)&dsh[dty * 4 + i][dtx * 4] = dd;
        }
    }
    __syncthreads();

    // phase 2: per-wave A-frags in registers (16 nodes/wave, split-bf16)
    bf16x8 ah[2], al[2];
    {
        int row = w * 16 + l16;
        #pragma unroll
        for (int s = 0; s < 2; ++s) {
            int k0 = s * 32 + g * 8;
            float4 f0 = *(float4*)&dsh[row][k0];
            float4 f1 = *(float4*)&dsh[row][k0 + 4];
            float fv[8] = {f0.x, f0.y, f0.z, f0.w, f1.x, f1.y, f1.z, f1.w};
            bf16x8 hv, lv;
            #pragma unroll
            for (int e = 0; e < 8; ++e) {
                unsigned short hh = f2bh(fv[e]);
                hv[e] = (short)hh;
                lv[e] = (short)f2bh(fv[e] - bh2f(hh));
            }
            ah[s] = hv; al[s] = lv;
        }
    }
    __syncthreads();   // dsh dead; w2 may now overwrite

    // phase 3: col chunks of 128
    for (int ch = 0; ch < 8; ++ch) {
        const int col0 = ch * 128;
        #pragma unroll
        for (int j = 0; j < 4; ++j) {
            int fi = tid + 256 * j;
            int c = fi >> 3, k8 = (fi & 7) * 8;
            *(uint4*)&w2h[c][k8] = *(const uint4*)(w2hg + (size_t)(col0 + c) * 64 + k8);
            *(uint4*)&w2l[c][k8] = *(const uint4*)(w2lg + (size_t)(col0 + c) * 64 + k8);
        }
        __syncthreads();
        f32x4 acc[8] = {};
        #pragma unroll
        for (int nf = 0; nf < 8; ++nf) {
            int c = nf * 16 + l16;
            #pragma unroll
            for (int s = 0; s < 2; ++s) {
                int k0 = s * 32 + g * 8;
                bf16x8 bh = *(const bf16x8*)&w2h[c][k0];
                bf16x8 bl = *(const bf16x8*)&w2l[c][k0];
                acc[nf] = __builtin_amdgcn_mfma_f32_16x16x32_bf16(ah[s], bh, acc[nf], 0, 0, 0);
                acc[nf] = __builtin_amdgcn_mfma_f32_16x16x32_bf16(al[s], bh, acc[nf], 0, 0, 0);
                acc[nf] = __builtin_amdgcn_mfma_f32_16x16x32_bf16(ah[s], bl, acc[nf], 0, 0, 0);
            }
        }
        #pragma unroll
        for (int nf = 0; nf < 8; ++nf) {
            int col = col0 + nf * 16 + l16;
            float b = bf2[col];
            #pragma unroll
            for (int r = 0; r < 4; ++r) {
                int node = node0 + w * 16 + g * 4 + r;
                if (node < NN)
                    out[(size_t)node * 1024 + col] = fmaxf(acc[nf][r] + b, 0.f);
            }
        }
        __syncthreads();
    }
}

extern "C" void kernel_launch(void* const* d_in, const int* in_sizes, int n_in,
                              void* d_out, int out_size, void* d_ws, size_t ws_size,
                              hipStream_t stream) {
    const float* x   = (const float*)d_in[0];
    const int* ei    = (const int*)d_in[1];
    const float* Wg1 = (const float*)d_in[2];
    const float* bg1 = (const float*)d_in[3];
    const float* Wg2 = (const float*)d_in[4];
    const float* bg2 = (const float*)d_in[5];
    const float* Wf1 = (const float*)d_in[6];
    const float* bf1 = (const float*)d_in[7];
    const float* Wf2 = (const float*)d_in[8];
    const float* bf2 = (const float*)d_in[9];
    float* out = (float*)d_out;
    float* ws  = (float*)d_ws;

    const int* src = ei;
    const int* dst = ei + EE;

    // ws (26 MB): dinv | g2 | z ; Wf2T tables overlay g2 after k_gather32.
    float* dinv = ws;
    float* g2   = ws + NN;
    float* z    = ws + NN + 32 * NN;
    unsigned short* wf2h = (unsigned short*)g2;            // 64K u16
    unsigned short* wf2l = wf2h + 64 * 1024;               // 64K u16

    // d_out scratch (all dead before k_decode writes out):
    float* g1 = out;                                       // 64N floats
    float* h  = out + (size_t)64 * NN;                     // 64N floats
    unsigned short* wg1img = (unsigned short*)h;           // 144K u16 (dead
                                                           //  before h write)
    int*      csr_src = (int*)(out + (size_t)128 * NN);    // E ints
    unsigned int* cnt     = (unsigned int*)(csr_src + EE); // N
    unsigned int* row_ptr = cnt + NN;                      // N
    unsigned int* cursor  = row_ptr + NN;                  // N

    k_init  <<<(NN + 255) / 256, 256, 0, stream>>>(cnt);
    k_count <<<(EE + 255) / 256, 256, 0, stream>>>(dst, cnt);
    k_dinv  <<<(NN + 255) / 256, 256, 0, stream>>>(cnt, dinv);
    k_scan  <<<1, 1024, 0, stream>>>(cnt, row_ptr, cursor);
    k_fill  <<<(EE + 255) / 256, 256, 0, stream>>>(src, dst, cursor, csr_src);
    k_prepW1<<<256, 256, 0, stream>>>(Wg1, wg1img);
    k_gemm1 <<<(NN + 63) / 64, 256, 0, stream>>>(x, wg1img, dinv, g1);
    k_gather64<<<(NN * 64 + 255) / 256, 256, 0, stream>>>(g1, csr_src, row_ptr, cnt, dinv, bg1, h);
    k_layer2<<<(NN + 63) / 64, 256, 0, stream>>>(h, Wg2, dinv, g2);
    k_gather32<<<(NN * 32 + 255) / 256, 256, 0, stream>>>(g2, csr_src, row_ptr, cnt, dinv, bg2, z);
    k_prepW2<<<256, 256, 0, stream>>>(Wf2, wf2h, wf2l);
    k_decode<<<(NN + 63) / 64, 256, 0, stream>>>(z, Wf1, bf1, wf2h, wf2l, bf2, out);
}

// Round 8
// 700.149 us; speedup vs baseline: 1.2663x; 1.1277x over previous
//
#include <hip/hip_runtime.h>

#define NN 100000
#define EE 1600000

using bf16x8 = __attribute__((ext_vector_type(8))) short;
using f32x4  = __attribute__((ext_vector_type(4))) float;

static __device__ __forceinline__ unsigned short f2bh(float f) {
    unsigned int u = __float_as_uint(f);
    return (unsigned short)((u + 0x7FFFu + ((u >> 16) & 1u)) >> 16);
}
static __device__ __forceinline__ float bh2f(unsigned short h) {
    return __uint_as_float(((unsigned int)h) << 16);
}

// split 8 floats into hi/lo bf16x8 via truncation (residual exact in fp32)
static __device__ __forceinline__ void split_pack(float4 a, float4 b,
                                                  bf16x8& h, bf16x8& l) {
    float f[8] = {a.x, a.y, a.z, a.w, b.x, b.y, b.z, b.w};
    union { bf16x8 v; unsigned int u[4]; } H, L;
    #pragma unroll
    for (int e = 0; e < 4; ++e) {
        unsigned int u0 = __float_as_uint(f[2 * e]);
        unsigned int u1 = __float_as_uint(f[2 * e + 1]);
        H.u[e] = (u0 >> 16) | (u1 & 0xFFFF0000u);
        float r0 = f[2 * e]     - __uint_as_float(u0 & 0xFFFF0000u);
        float r1 = f[2 * e + 1] - __uint_as_float(u1 & 0xFFFF0000u);
        L.u[e] = (__float_as_uint(r0) >> 16) | (__float_as_uint(r1) & 0xFFFF0000u);
    }
    h = H.v; l = L.v;
}

// ---------------- cursor init ----------------
__global__ __launch_bounds__(256) void k_init(unsigned int* cursor) {
    int v = blockIdx.x * 256 + threadIdx.x;
    if (v < NN) cursor[v] = 0u;
}

// ---------------- bucket fill: bkt[d*64 + pos] = src; cursor ends as degree --
__global__ __launch_bounds__(256) void k_fill(const int* __restrict__ src,
        const int* __restrict__ dst, unsigned int* cursor, int* __restrict__ bkt) {
    int e = blockIdx.x * 256 + threadIdx.x;
    if (e < EE) {
        int d = dst[e];
        unsigned int pos = atomicAdd(&cursor[d], 1u);
        bkt[(size_t)d * 64 + pos] = src[e];
    }
}

__global__ __launch_bounds__(256) void k_dinv(const unsigned int* __restrict__ deg, float* dinv) {
    int v = blockIdx.x * 256 + threadIdx.x;
    if (v < NN) dinv[v] = rsqrtf((float)(deg[v] + 1u));
}

// ------- prep: Wg1 [1024][64] -> chunked LDS image [16][2][64][72] u16 ------
__global__ __launch_bounds__(256) void k_prepW1(const float* __restrict__ W,
        unsigned short* __restrict__ img) {
    int t = blockIdx.x * 256 + threadIdx.x;       // 65536
    int k = t >> 6, c = t & 63;
    float f = W[k * 64 + c];
    unsigned short h = f2bh(f);
    size_t base = (size_t)(k >> 6) * 9216 + (size_t)c * 72 + (k & 63);
    img[base] = h;
    img[base + 4608] = f2bh(f - bh2f(h));
}

// ---------------- prep: Wf2 [64][1024] -> transposed split-bf16 [1024][64] --
__global__ __launch_bounds__(256) void k_prepW2(const float* __restrict__ W,
        unsigned short* __restrict__ wh, unsigned short* __restrict__ wl) {
    int t = blockIdx.x * 256 + threadIdx.x;       // 65536
    int k = t >> 10, c = t & 1023;
    float f = W[k * 1024 + c];
    unsigned short h = f2bh(f);
    wh[c * 64 + k] = h;
    wl[c * 64 + k] = f2bh(f - bh2f(h));
}

// ---------------- GEMM1 v4: 128 rows/block, x-loads-first, B LDS dbuf -------
// 4 waves; wave = 2 row-frags (16 rows each, +64 apart) x 64 cols.
__global__ __launch_bounds__(256) void k_gemm1(const float* __restrict__ x,
        const unsigned short* __restrict__ wimg,
        const float* __restrict__ dinv, float* __restrict__ g1) {
    __shared__ __align__(16) unsigned short bs[2][2][64][72];   // 36864 B
    const int tid = threadIdx.x;
    const int lane = tid & 63, w = tid >> 6;
    const int l16 = lane & 15, g = lane >> 4;
    const int row0 = blockIdx.x * 128 + w * 16;
    const int rA0 = row0 + l16, rA1 = row0 + 64 + l16;
    const bool ok0 = rA0 < NN, ok1 = rA1 < NN;
    const float* xp0 = x + (size_t)rA0 * 1024;
    const float* xp1 = x + (size_t)rA1 * 1024;
    f32x4 acc[2][4] = {};
    // prologue: stage chunk 0 into buf 0
    {
        const char* gb = (const char*)wimg;
        char* lb = (char*)&bs[0][0][0][0];
        for (int j = w; j < 18; j += 4)
            __builtin_amdgcn_global_load_lds((const unsigned int*)(gb + j * 1024 + lane * 16),
                                             (unsigned int*)(lb + j * 1024), 16, 0, 0);
    }
    __syncthreads();
    int cur = 0;
    for (int t = 0; t < 16; ++t) {
        const int kc = t * 64;
        // (a) x loads FIRST (so their consumption doesn't drain staging)
        float4 xr[2][2][2];   // [row][s][half]
        #pragma unroll
        for (int s = 0; s < 2; ++s) {
            const int k0 = kc + s * 32 + g * 8;
            xr[0][s][0] = ok0 ? *(const float4*)(xp0 + k0)     : make_float4(0.f,0.f,0.f,0.f);
            xr[0][s][1] = ok0 ? *(const float4*)(xp0 + k0 + 4) : make_float4(0.f,0.f,0.f,0.f);
            xr[1][s][0] = ok1 ? *(const float4*)(xp1 + k0)     : make_float4(0.f,0.f,0.f,0.f);
            xr[1][s][1] = ok1 ? *(const float4*)(xp1 + k0 + 4) : make_float4(0.f,0.f,0.f,0.f);
        }
        // (b) issue staging for next chunk
        if (t < 15) {
            const char* gb = (const char*)wimg + (size_t)(t + 1) * 18432;
            char* lb = (char*)&bs[cur ^ 1][0][0][0];
            for (int j = w; j < 18; j += 4)
                __builtin_amdgcn_global_load_lds((const unsigned int*)(gb + j * 1024 + lane * 16),
                                                 (unsigned int*)(lb + j * 1024), 16, 0, 0);
        }
        // (c) compute (staging stays in flight)
        #pragma unroll
        for (int s = 0; s < 2; ++s) {
            bf16x8 ah0, al0, ah1, al1;
            split_pack(xr[0][s][0], xr[0][s][1], ah0, al0);
            split_pack(xr[1][s][0], xr[1][s][1], ah1, al1);
            const int koff = s * 32 + g * 8;
            #pragma unroll
            for (int nf = 0; nf < 4; ++nf) {
                bf16x8 bh = *(const bf16x8*)&bs[cur][0][nf * 16 + l16][koff];
                bf16x8 bl = *(const bf16x8*)&bs[cur][1][nf * 16 + l16][koff];
                acc[0][nf] = __builtin_amdgcn_mfma_f32_16x16x32_bf16(ah0, bh, acc[0][nf], 0, 0, 0);
                acc[1][nf] = __builtin_amdgcn_mfma_f32_16x16x32_bf16(ah1, bh, acc[1][nf], 0, 0, 0);
                acc[0][nf] = __builtin_amdgcn_mfma_f32_16x16x32_bf16(al0, bh, acc[0][nf], 0, 0, 0);
                acc[1][nf] = __builtin_amdgcn_mfma_f32_16x16x32_bf16(al1, bh, acc[1][nf], 0, 0, 0);
                acc[0][nf] = __builtin_amdgcn_mfma_f32_16x16x32_bf16(ah0, bl, acc[0][nf], 0, 0, 0);
                acc[1][nf] = __builtin_amdgcn_mfma_f32_16x16x32_bf16(ah1, bl, acc[1][nf], 0, 0, 0);
            }
        }
        __syncthreads();
        cur ^= 1;
    }
    #pragma unroll
    for (int mf = 0; mf < 2; ++mf) {
        #pragma unroll
        for (int r = 0; r < 4; ++r) {
            int node = row0 + mf * 64 + g * 4 + r;
            if (node < NN) {
                float di = dinv[node];
                #pragma unroll
                for (int nf = 0; nf < 4; ++nf)
                    g1[(size_t)node * 64 + nf * 16 + l16] = acc[mf][nf][r] * di;
            }
        }
    }
}

// ------- gather 64ch (bucket) + fused norm/bias/relu ------------------------
__global__ __launch_bounds__(256) void k_gather64(const float* __restrict__ g1,
        const int* __restrict__ bkt, const unsigned int* __restrict__ deg,
        const float* __restrict__ dinv, const float* __restrict__ bg1,
        float* __restrict__ h) {
    int wv = (blockIdx.x * 256 + threadIdx.x) >> 6;   // wave = node
    int lane = threadIdx.x & 63;
    if (wv >= NN) return;
    unsigned int n = deg[wv];
    const int* b = bkt + (size_t)wv * 64;
    float sum = g1[(size_t)wv * 64 + lane];           // self loop
    unsigned int i = 0;
    for (; i + 4 <= n; i += 4) {
        int s0 = b[i], s1 = b[i + 1], s2 = b[i + 2], s3 = b[i + 3];
        float v0 = g1[(size_t)s0 * 64 + lane];
        float v1 = g1[(size_t)s1 * 64 + lane];
        float v2 = g1[(size_t)s2 * 64 + lane];
        float v3 = g1[(size_t)s3 * 64 + lane];
        sum += (v0 + v1) + (v2 + v3);
    }
    for (; i < n; ++i) sum += g1[(size_t)b[i] * 64 + lane];
    h[(size_t)wv * 64 + lane] = fmaxf(sum * dinv[wv] + bg1[lane], 0.f);
}

// ---------------- layer2 GEMM (fp32, tiny): g2 = (h @ Wg2) * dinv[row] ------
__global__ __launch_bounds__(256) void k_layer2(const float* __restrict__ h,
        const float* __restrict__ Wg2, const float* __restrict__ dinv,
        float* __restrict__ g2) {
    __shared__ __align__(16) float as[64][68];
    __shared__ __align__(16) float wsh[64][32];
    const int tid = threadIdx.x;
    const int node0 = blockIdx.x * 64;
    {
        const int lr = tid >> 4, lk = (tid & 15) * 4;
        #pragma unroll
        for (int l = 0; l < 4; ++l) {
            int r = lr + l * 16, v = node0 + r;
            float4 a = make_float4(0.f, 0.f, 0.f, 0.f);
            if (v < NN) a = *(const float4*)(h + (size_t)v * 64 + lk);
            *(float4*)&as[r][lk] = a;
        }
        const int wr = tid >> 3, wk = (tid & 7) * 4;
        #pragma unroll
        for (int l = 0; l < 2; ++l) {
            int r = wr + l * 32;
            *(float4*)&wsh[r][wk] = *(const float4*)(Wg2 + (size_t)r * 32 + wk);
        }
    }
    __syncthreads();
    const int tx = tid & 7, ty = tid >> 3;
    float acc[2][4] = {{0.f}};
    for (int kk = 0; kk < 64; kk += 4) {
        float wv[4][4];
        #pragma unroll
        for (int j = 0; j < 4; ++j)
            *(float4*)&wv[j][0] = *(const float4*)&wsh[kk + j][tx * 4];
        #pragma unroll
        for (int i = 0; i < 2; ++i) {
            float xv[4];
            *(float4*)&xv[0] = *(const float4*)&as[ty * 2 + i][kk];
            #pragma unroll
            for (int j = 0; j < 4; ++j) {
                #pragma unroll
                for (int c = 0; c < 4; ++c)
                    acc[i][c] += xv[j] * wv[j][c];
            }
        }
    }
    #pragma unroll
    for (int i = 0; i < 2; ++i) {
        int v = node0 + ty * 2 + i;
        if (v < NN) {
            float di = dinv[v];
            float4 o;
            o.x = acc[i][0] * di; o.y = acc[i][1] * di;
            o.z = acc[i][2] * di; o.w = acc[i][3] * di;
            *(float4*)(g2 + (size_t)v * 32 + tx * 4) = o;
        }
    }
}

// ------- gather 32ch (bucket) + fused norm/bias -----------------------------
__global__ __launch_bounds__(256) void k_gather32(const float* __restrict__ g2,
        const int* __restrict__ bkt, const unsigned int* __restrict__ deg,
        const float* __restrict__ dinv, const float* __restrict__ bg2,
        float* __restrict__ z) {
    int node = (blockIdx.x * 256 + threadIdx.x) >> 5;  // half-wave = node
    int c = threadIdx.x & 31;
    if (node >= NN) return;
    unsigned int n = deg[node];
    const int* b = bkt + (size_t)node * 64;
    float sum = g2[(size_t)node * 32 + c];
    unsigned int i = 0;
    for (; i + 4 <= n; i += 4) {
        int s0 = b[i], s1 = b[i + 1], s2 = b[i + 2], s3 = b[i + 3];
        float v0 = g2[(size_t)s0 * 32 + c];
        float v1 = g2[(size_t)s1 * 32 + c];
        float v2 = g2[(size_t)s2 * 32 + c];
        float v3 = g2[(size_t)s3 * 32 + c];
        sum += (v0 + v1) + (v2 + v3);
    }
    for (; i < n; ++i) sum += g2[(size_t)b[i] * 32 + c];
    z[(size_t)node * 32 + c] = sum * dinv[node] + bg2[c];
}

// ---------------- decode v2: reg-prefetch of Wf2 chunks ---------------------
__global__ __launch_bounds__(256) void k_decode(const float* __restrict__ z,
        const float* __restrict__ Wf1, const float* __restrict__ bf1,
        const unsigned short* __restrict__ w2hg, const unsigned short* __restrict__ w2lg,
        const float* __restrict__ bf2, float* __restrict__ out) {
    __shared__ __align__(16) unsigned char smem[36864];
    float (*dsh)[68] = (float (*)[68])smem;                          // 64x68 f
    float (*zs)[36]  = (float (*)[36])(smem + 17408);                // 64x36 f
    float (*w1s)[64] = (float (*)[64])(smem + 17408 + 9216);         // 32x64 f
    unsigned short (*w2h)[72] = (unsigned short (*)[72])smem;        // 128x72 u16
    unsigned short (*w2l)[72] = (unsigned short (*)[72])(smem + 18432);
    const int tid = threadIdx.x;
    const int lane = tid & 63, w = tid >> 6;
    const int l16 = lane & 15, g = lane >> 4;
    const int node0 = blockIdx.x * 64;

    // prefetch w2 chunk 0 into regs (hides under phase 1/2)
    uint4 ph[4], pl[4];
    #pragma unroll
    for (int j = 0; j < 4; ++j) {
        int fi = tid + 256 * j;
        int c = fi >> 3, k8 = (fi & 7) * 8;
        ph[j] = *(const uint4*)(w2hg + (size_t)c * 64 + k8);
        pl[j] = *(const uint4*)(w2lg + (size_t)c * 64 + k8);
    }

    // phase 1a: stage z [64][32] and Wf1 [32][64]
    #pragma unroll
    for (int j = 0; j < 2; ++j) {
        int fi = tid + 256 * j;
        int v = fi >> 3, m4 = (fi & 7) * 4;
        float4 zz = make_float4(0.f, 0.f, 0.f, 0.f);
        if (node0 + v < NN) zz = *(const float4*)(z + (size_t)(node0 + v) * 32 + m4);
        *(float4*)&zs[v][m4] = zz;
    }
    #pragma unroll
    for (int j = 0; j < 2; ++j) {
        int fi = tid + 256 * j;
        int r = fi >> 4, c4 = (fi & 15) * 4;
        *(float4*)&w1s[r][c4] = *(const float4*)(Wf1 + (size_t)r * 64 + c4);
    }
    __syncthreads();

    // phase 1b: d = relu(z @ Wf1 + bf1) -> dsh (fp32)
    {
        const int dtx = tid & 15, dty = tid >> 4;
        float acc[4][4] = {{0.f}};
        for (int m = 0; m < 32; m += 4) {
            float wv[4][4];
            #pragma unroll
            for (int j = 0; j < 4; ++j)
                *(float4*)&wv[j][0] = *(const float4*)&w1s[m + j][dtx * 4];
            #pragma unroll
            for (int i = 0; i < 4; ++i) {
                float zv[4];
                *(float4*)&zv[0] = *(const float4*)&zs[dty * 4 + i][m];
                #pragma unroll
                for (int j = 0; j < 4; ++j) {
                    #pragma unroll
                    for (int c = 0; c < 4; ++c)
                        acc[i][c] += zv[j] * wv[j][c];
                }
            }
        }
        float4 b4 = *(const float4*)(bf1 + dtx * 4);
        #pragma unroll
        for (int i = 0; i < 4; ++i) {
            float4 dd;
            dd.x = fmaxf(acc[i][0] + b4.x, 0.f);
            dd.y = fmaxf(acc[i][1] + b4.y, 0.f);
            dd.z = fmaxf(acc[i][2] + b4.z, 0.f);
            dd.w = fmaxf(acc[i][3] + b4.w, 0.f);
            *(float4*)&dsh[dty * 4 + i][dtx * 4] = dd;
        }
    }
    __syncthreads();

    // phase 2: per-wave A-frags in registers (16 nodes/wave, split-bf16)
    bf16x8 ah[2], al[2];
    {
        int row = w * 16 + l16;
        #pragma unroll
        for (int s = 0; s < 2; ++s) {
            int k0 = s * 32 + g * 8;
            float4 f0 = *(float4*)&dsh[row][k0];
            float4 f1 = *(float4*)&dsh[row][k0 + 4];
            float fv[8] = {f0.x, f0.y, f0.z, f0.w, f1.x, f1.y, f1.z, f1.w};
            bf16x8 hv, lv;
            #pragma unroll
            for (int e = 0; e < 8; ++e) {
                unsigned short hh = f2bh(fv[e]);
                hv[e] = (short)hh;
                lv[e] = (short)f2bh(fv[e] - bh2f(hh));
            }
            ah[s] = hv; al[s] = lv;
        }
    }
    __syncthreads();   // dsh dead; w2 may now overwrite

    // write prefetched chunk 0 to LDS
    #pragma unroll
    for (int j = 0; j < 4; ++j) {
        int fi = tid + 256 * j;
        int c = fi >> 3, k8 = (fi & 7) * 8;
        *(uint4*)&w2h[c][k8] = ph[j];
        *(uint4*)&w2l[c][k8] = pl[j];
    }
    __syncthreads();

    // phase 3: col chunks of 128, next chunk prefetched in regs under MFMA
    for (int ch = 0; ch < 8; ++ch) {
        if (ch < 7) {
            const int col0n = (ch + 1) * 128;
            #pragma unroll
            for (int j = 0; j < 4; ++j) {
                int fi = tid + 256 * j;
                int c = fi >> 3, k8 = (fi & 7) * 8;
                ph[j] = *(const uint4*)(w2hg + (size_t)(col0n + c) * 64 + k8);
                pl[j] = *(const uint4*)(w2lg + (size_t)(col0n + c) * 64 + k8);
            }
        }
        const int col0 = ch * 128;
        f32x4 acc[8] = {};
        #pragma unroll
        for (int nf = 0; nf < 8; ++nf) {
            int c = nf * 16 + l16;
            #pragma unroll
            for (int s = 0; s < 2; ++s) {
                int k0 = s * 32 + g * 8;
                bf16x8 bh = *(const bf16x8*)&w2h[c][k0];
                bf16x8 bl = *(const bf16x8*)&w2l[c][k0];
                acc[nf] = __builtin_amdgcn_mfma_f32_16x16x32_bf16(ah[s], bh, acc[nf], 0, 0, 0);
                acc[nf] = __builtin_amdgcn_mfma_f32_16x16x32_bf16(al[s], bh, acc[nf], 0, 0, 0);
                acc[nf] = __builtin_amdgcn_mfma_f32_16x16x32_bf16(ah[s], bl, acc[nf], 0, 0, 0);
            }
        }
        #pragma unroll
        for (int nf = 0; nf < 8; ++nf) {
            int col = col0 + nf * 16 + l16;
            float b = bf2[col];
            #pragma unroll
            for (int r = 0; r < 4; ++r) {
                int node = node0 + w * 16 + g * 4 + r;
                if (node < NN)
                    out[(size_t)node * 1024 + col] = fmaxf(acc[nf][r] + b, 0.f);
            }
        }
        __syncthreads();              // all LDS reads done (also lands prefetch)
        if (ch < 7) {
            #pragma unroll
            for (int j = 0; j < 4; ++j) {
                int fi = tid + 256 * j;
                int c = fi >> 3, k8 = (fi & 7) * 8;
                *(uint4*)&w2h[c][k8] = ph[j];
                *(uint4*)&w2l[c][k8] = pl[j];
            }
            __syncthreads();
        }
    }
}

extern "C" void kernel_launch(void* const* d_in, const int* in_sizes, int n_in,
                              void* d_out, int out_size, void* d_ws, size_t ws_size,
                              hipStream_t stream) {
    const float* x   = (const float*)d_in[0];
    const int* ei    = (const int*)d_in[1];
    const float* Wg1 = (const float*)d_in[2];
    const float* bg1 = (const float*)d_in[3];
    const float* Wg2 = (const float*)d_in[4];
    const float* bg2 = (const float*)d_in[5];
    const float* Wf1 = (const float*)d_in[6];
    const float* bf1 = (const float*)d_in[7];
    const float* Wf2 = (const float*)d_in[8];
    const float* bf2 = (const float*)d_in[9];
    float* out = (float*)d_out;
    float* ws  = (float*)d_ws;

    const int* src = ei;
    const int* dst = ei + EE;

    // ws (26 MB): dinv | g2 | z ; Wf2T split tables overlay g2 after gather32.
    float* dinv = ws;
    float* g2   = ws + NN;
    float* z    = ws + NN + 32 * NN;
    unsigned short* wf2h = (unsigned short*)g2;            // 64K u16
    unsigned short* wf2l = wf2h + 64 * 1024;               // 64K u16

    // d_out scratch (all dead before k_decode writes out):
    float* g1 = out;                                       // 64N floats
    float* h  = out + (size_t)64 * NN;                     // 64N floats
    int* bkt  = (int*)(out + (size_t)128 * NN);            // 64N ints (cap 64)
    unsigned int* cursor = (unsigned int*)(bkt + (size_t)64 * NN);  // N (= degree)
    unsigned short* wg1img = (unsigned short*)(cursor + NN);        // 147456 u16

    k_init  <<<(NN + 255) / 256, 256, 0, stream>>>(cursor);
    k_fill  <<<(EE + 255) / 256, 256, 0, stream>>>(src, dst, cursor, bkt);
    k_dinv  <<<(NN + 255) / 256, 256, 0, stream>>>(cursor, dinv);
    k_prepW1<<<256, 256, 0, stream>>>(Wg1, wg1img);
    k_gemm1 <<<(NN + 127) / 128, 256, 0, stream>>>(x, wg1img, dinv, g1);
    k_gather64<<<(NN * 64 + 255) / 256, 256, 0, stream>>>(g1, bkt, cursor, dinv, bg1, h);
    k_layer2<<<(NN + 63) / 64, 256, 0, stream>>>(h, Wg2, dinv, g2);
    k_gather32<<<(NN * 32 + 255) / 256, 256, 0, stream>>>(g2, bkt, cursor, dinv, bg2, z);
    k_prepW2<<<256, 256, 0, stream>>>(Wf2, wf2h, wf2l);
    k_decode<<<(NN + 63) / 64, 256, 0, stream>>>(z, Wf1, bf1, wf2h, wf2l, bf2, out);
}

// Round 9
// 609.095 us; speedup vs baseline: 1.4556x; 1.1495x over previous
//
#include <hip/hip_runtime.h>

#define NN 100000
#define EE 1600000

using bf16x8 = __attribute__((ext_vector_type(8))) short;
using f32x4  = __attribute__((ext_vector_type(4))) float;

static __device__ __forceinline__ unsigned short f2bh(float f) {
    unsigned int u = __float_as_uint(f);
    return (unsigned short)((u + 0x7FFFu + ((u >> 16) & 1u)) >> 16);
}
static __device__ __forceinline__ float bh2f(unsigned short h) {
    return __uint_as_float(((unsigned int)h) << 16);
}

// split 8 floats into hi/lo bf16x8 via truncation (residual exact in fp32)
static __device__ __forceinline__ void split_pack(float4 a, float4 b,
                                                  bf16x8& h, bf16x8& l) {
    float f[8] = {a.x, a.y, a.z, a.w, b.x, b.y, b.z, b.w};
    union { bf16x8 v; unsigned int u[4]; } H, L;
    #pragma unroll
    for (int e = 0; e < 4; ++e) {
        unsigned int u0 = __float_as_uint(f[2 * e]);
        unsigned int u1 = __float_as_uint(f[2 * e + 1]);
        H.u[e] = (u0 >> 16) | (u1 & 0xFFFF0000u);
        float r0 = f[2 * e]     - __uint_as_float(u0 & 0xFFFF0000u);
        float r1 = f[2 * e + 1] - __uint_as_float(u1 & 0xFFFF0000u);
        L.u[e] = (__float_as_uint(r0) >> 16) | (__float_as_uint(r1) & 0xFFFF0000u);
    }
    h = H.v; l = L.v;
}

// ---------------- cursor init ----------------
__global__ __launch_bounds__(256) void k_init(unsigned int* cursor) {
    int v = blockIdx.x * 256 + threadIdx.x;
    if (v < NN) cursor[v] = 0u;
}

// -------- bucket fill: bkt[d*64 + pos] = src; cursor ends as degree ---------
__global__ __launch_bounds__(256) void k_fill(const int* __restrict__ src,
        const int* __restrict__ dst, unsigned int* cursor, int* __restrict__ bkt) {
    int e = blockIdx.x * 256 + threadIdx.x;
    if (e < EE) {
        int d = dst[e];
        unsigned int pos = atomicAdd(&cursor[d], 1u);
        bkt[(size_t)d * 64 + pos] = src[e];
    }
}

__global__ __launch_bounds__(256) void k_dinv(const unsigned int* __restrict__ deg, float* dinv) {
    int v = blockIdx.x * 256 + threadIdx.x;
    if (v < NN) dinv[v] = rsqrtf((float)(deg[v] + 1u));
}

// ------- prep: Wg1 [1024][64] -> 32 chunked LDS images [32][2][64][36] u16 --
// chunk = k/32; per chunk image 9216 B = what gemm1 stages linearly.
__global__ __launch_bounds__(256) void k_prepW1(const float* __restrict__ W,
        unsigned short* __restrict__ img) {
    int t = blockIdx.x * 256 + threadIdx.x;       // 65536
    int k = t >> 6, c = t & 63;
    float f = W[k * 64 + c];
    unsigned short h = f2bh(f);
    int chunk = k >> 5, kk = k & 31;
    size_t base = (size_t)chunk * 4608 + (size_t)c * 36 + kk;   // u16 units
    img[base] = h;
    img[base + 2304] = f2bh(f - bh2f(h));
}

// ---------------- prep: Wf2 [64][1024] -> transposed split-bf16 [1024][64] --
__global__ __launch_bounds__(256) void k_prepW2(const float* __restrict__ W,
        unsigned short* __restrict__ wh, unsigned short* __restrict__ wl) {
    int t = blockIdx.x * 256 + threadIdx.x;       // 65536
    int k = t >> 10, c = t & 1023;
    float f = W[k * 1024 + c];
    unsigned short h = f2bh(f);
    wh[c * 64 + k] = h;
    wl[c * 64 + k] = f2bh(f - bh2f(h));
}

// ---------------- GEMM1 v5: 64 rows/block, 32-K chunks, dbuf B, x-prefetch --
__global__ __launch_bounds__(256) void k_gemm1(const float* __restrict__ x,
        const unsigned short* __restrict__ wimg,
        const float* __restrict__ dinv, float* __restrict__ g1) {
    __shared__ __align__(16) unsigned short bs[2][2][64][36];   // 18432 B
    const int tid = threadIdx.x;
    const int lane = tid & 63, w = tid >> 6;
    const int l16 = lane & 15, g = lane >> 4;
    const int row0 = blockIdx.x * 64;
    const int rA = row0 + w * 16 + l16;
    const bool okA = rA < NN;
    const float* xp = x + (size_t)rA * 1024 + g * 8;
    const char* wb = (const char*)wimg;
    f32x4 acc[4] = {};
    // prologue: stage chunk 0, load x chunk 0
    for (int j = w; j < 9; j += 4)
        __builtin_amdgcn_global_load_lds((const unsigned int*)(wb + j * 1024 + lane * 16),
                                         (unsigned int*)((char*)&bs[0][0][0][0] + j * 1024), 16, 0, 0);
    float4 xr0 = make_float4(0.f,0.f,0.f,0.f), xr1 = xr0;
    if (okA) { xr0 = *(const float4*)(xp); xr1 = *(const float4*)(xp + 4); }
    __syncthreads();
    int cur = 0;
    for (int t = 0; t < 32; ++t) {
        float4 nx0 = make_float4(0.f,0.f,0.f,0.f), nx1 = nx0;
        if (t < 31) {
            const char* gb = wb + (size_t)(t + 1) * 9216;
            char* lb = (char*)&bs[cur ^ 1][0][0][0];
            for (int j = w; j < 9; j += 4)
                __builtin_amdgcn_global_load_lds((const unsigned int*)(gb + j * 1024 + lane * 16),
                                                 (unsigned int*)(lb + j * 1024), 16, 0, 0);
            if (okA) { nx0 = *(const float4*)(xp + (t + 1) * 32);
                       nx1 = *(const float4*)(xp + (t + 1) * 32 + 4); }
        }
        bf16x8 ah, al;
        split_pack(xr0, xr1, ah, al);
        #pragma unroll
        for (int nf = 0; nf < 4; ++nf) {
            bf16x8 bh = *(const bf16x8*)&bs[cur][0][nf * 16 + l16][g * 8];
            bf16x8 bl = *(const bf16x8*)&bs[cur][1][nf * 16 + l16][g * 8];
            acc[nf] = __builtin_amdgcn_mfma_f32_16x16x32_bf16(ah, bh, acc[nf], 0, 0, 0);
            acc[nf] = __builtin_amdgcn_mfma_f32_16x16x32_bf16(al, bh, acc[nf], 0, 0, 0);
            acc[nf] = __builtin_amdgcn_mfma_f32_16x16x32_bf16(ah, bl, acc[nf], 0, 0, 0);
        }
        __syncthreads();
        xr0 = nx0; xr1 = nx1; cur ^= 1;
    }
    #pragma unroll
    for (int r = 0; r < 4; ++r) {
        int node = row0 + w * 16 + g * 4 + r;
        if (node < NN) {
            float di = dinv[node];
            #pragma unroll
            for (int nf = 0; nf < 4; ++nf)
                g1[(size_t)node * 64 + nf * 16 + l16] = acc[nf][r] * di;
        }
    }
}

// ------- gather 64ch (bucket) + fused norm/bias/relu ------------------------
__global__ __launch_bounds__(256) void k_gather64(const float* __restrict__ g1,
        const int* __restrict__ bkt, const unsigned int* __restrict__ deg,
        const float* __restrict__ dinv, const float* __restrict__ bg1,
        float* __restrict__ h) {
    int wv = (blockIdx.x * 256 + threadIdx.x) >> 6;   // wave = node
    int lane = threadIdx.x & 63;
    if (wv >= NN) return;
    unsigned int n = deg[wv];
    const int* b = bkt + (size_t)wv * 64;
    float sum = g1[(size_t)wv * 64 + lane];           // self loop
    unsigned int i = 0;
    for (; i + 4 <= n; i += 4) {
        int s0 = b[i], s1 = b[i + 1], s2 = b[i + 2], s3 = b[i + 3];
        float v0 = g1[(size_t)s0 * 64 + lane];
        float v1 = g1[(size_t)s1 * 64 + lane];
        float v2 = g1[(size_t)s2 * 64 + lane];
        float v3 = g1[(size_t)s3 * 64 + lane];
        sum += (v0 + v1) + (v2 + v3);
    }
    for (; i < n; ++i) sum += g1[(size_t)b[i] * 64 + lane];
    h[(size_t)wv * 64 + lane] = fmaxf(sum * dinv[wv] + bg1[lane], 0.f);
}

// ---------------- layer2 GEMM (fp32, tiny): g2 = (h @ Wg2) * dinv[row] ------
__global__ __launch_bounds__(256) void k_layer2(const float* __restrict__ h,
        const float* __restrict__ Wg2, const float* __restrict__ dinv,
        float* __restrict__ g2) {
    __shared__ __align__(16) float as[64][68];
    __shared__ __align__(16) float wsh[64][32];
    const int tid = threadIdx.x;
    const int node0 = blockIdx.x * 64;
    {
        const int lr = tid >> 4, lk = (tid & 15) * 4;
        #pragma unroll
        for (int l = 0; l < 4; ++l) {
            int r = lr + l * 16, v = node0 + r;
            float4 a = make_float4(0.f, 0.f, 0.f, 0.f);
            if (v < NN) a = *(const float4*)(h + (size_t)v * 64 + lk);
            *(float4*)&as[r][lk] = a;
        }
        const int wr = tid >> 3, wk = (tid & 7) * 4;
        #pragma unroll
        for (int l = 0; l < 2; ++l) {
            int r = wr + l * 32;
            *(float4*)&wsh[r][wk] = *(const float4*)(Wg2 + (size_t)r * 32 + wk);
        }
    }
    __syncthreads();
    const int tx = tid & 7, ty = tid >> 3;
    float acc[2][4] = {{0.f}};
    for (int kk = 0; kk < 64; kk += 4) {
        float wv[4][4];
        #pragma unroll
        for (int j = 0; j < 4; ++j)
            *(float4*)&wv[j][0] = *(const float4*)&wsh[kk + j][tx * 4];
        #pragma unroll
        for (int i = 0; i < 2; ++i) {
            float xv[4];
            *(float4*)&xv[0] = *(const float4*)&as[ty * 2 + i][kk];
            #pragma unroll
            for (int j = 0; j < 4; ++j) {
                #pragma unroll
                for (int c = 0; c < 4; ++c)
                    acc[i][c] += xv[j] * wv[j][c];
            }
        }
    }
    #pragma unroll
    for (int i = 0; i < 2; ++i) {
        int v = node0 + ty * 2 + i;
        if (v < NN) {
            float di = dinv[v];
            float4 o;
            o.x = acc[i][0] * di; o.y = acc[i][1] * di;
            o.z = acc[i][2] * di; o.w = acc[i][3] * di;
            *(float4*)(g2 + (size_t)v * 32 + tx * 4) = o;
        }
    }
}

// ------- gather 32ch (bucket) + fused norm/bias -----------------------------
__global__ __launch_bounds__(256) void k_gather32(const float* __restrict__ g2,
        const int* __restrict__ bkt, const unsigned int* __restrict__ deg,
        const float* __restrict__ dinv, const float* __restrict__ bg2,
        float* __restrict__ z) {
    int node = (blockIdx.x * 256 + threadIdx.x) >> 5;  // half-wave = node
    int c = threadIdx.x & 31;
    if (node >= NN) return;
    unsigned int n = deg[node];
    const int* b = bkt + (size_t)node * 64;
    float sum = g2[(size_t)node * 32 + c];
    unsigned int i = 0;
    for (; i + 4 <= n; i += 4) {
        int s0 = b[i], s1 = b[i + 1], s2 = b[i + 2], s3 = b[i + 3];
        float v0 = g2[(size_t)s0 * 32 + c];
        float v1 = g2[(size_t)s1 * 32 + c];
        float v2 = g2[(size_t)s2 * 32 + c];
        float v3 = g2[(size_t)s3 * 32 + c];
        sum += (v0 + v1) + (v2 + v3);
    }
    for (; i < n; ++i) sum += g2[(size_t)b[i] * 32 + c];
    z[(size_t)node * 32 + c] = sum * dinv[node] + bg2[c];
}

// ---------------- decode v3: 16 chunks x 64 cols, LDS-outstage epilogue -----
__global__ __launch_bounds__(256) void k_decode(const float* __restrict__ z,
        const float* __restrict__ Wf1, const float* __restrict__ bf1,
        const unsigned short* __restrict__ w2hg, const unsigned short* __restrict__ w2lg,
        const float* __restrict__ bf2, float* __restrict__ out) {
    __shared__ __align__(16) unsigned char smem[35328];
    float (*dsh)[68] = (float (*)[68])smem;                          // 64x68 f
    float (*zs)[36]  = (float (*)[36])(smem + 17408);                // 64x36 f
    float (*w1s)[64] = (float (*)[64])(smem + 26624);                // 32x64 f
    unsigned short (*w2h)[72] = (unsigned short (*)[72])smem;        // 64x72 u16
    unsigned short (*w2l)[72] = (unsigned short (*)[72])(smem + 9216);
    float (*ost)[66] = (float (*)[66])(smem + 18432);                // 64x66 f
    const int tid = threadIdx.x;
    const int lane = tid & 63, w = tid >> 6;
    const int l16 = lane & 15, g = lane >> 4;
    const int node0 = blockIdx.x * 64;

    // prefetch w2 chunk 0 into regs (64 cols x 64 k compact = 2 uint4/thread/tab)
    uint4 ph[2], pl[2];
    #pragma unroll
    for (int j = 0; j < 2; ++j) {
        int fi = tid + 256 * j;
        int c = fi >> 3, k8 = (fi & 7) * 8;
        ph[j] = *(const uint4*)(w2hg + (size_t)c * 64 + k8);
        pl[j] = *(const uint4*)(w2lg + (size_t)c * 64 + k8);
    }

    // phase 1a: stage z [64][32] and Wf1 [32][64]
    #pragma unroll
    for (int j = 0; j < 2; ++j) {
        int fi = tid + 256 * j;
        int v = fi >> 3, m4 = (fi & 7) * 4;
        float4 zz = make_float4(0.f, 0.f, 0.f, 0.f);
        if (node0 + v < NN) zz = *(const float4*)(z + (size_t)(node0 + v) * 32 + m4);
        *(float4*)&zs[v][m4] = zz;
    }
    #pragma unroll
    for (int j = 0; j < 2; ++j) {
        int fi = tid + 256 * j;
        int r = fi >> 4, c4 = (fi & 15) * 4;
        *(float4*)&w1s[r][c4] = *(const float4*)(Wf1 + (size_t)r * 64 + c4);
    }
    __syncthreads();

    // phase 1b: d = relu(z @ Wf1 + bf1) -> dsh (fp32)
    {
        const int dtx = tid & 15, dty = tid >> 4;
        float acc[4][4] = {{0.f}};
        for (int m = 0; m < 32; m += 4) {
            float wv[4][4];
            #pragma unroll
            for (int j = 0; j < 4; ++j)
                *(float4*)&wv[j][0] = *(const float4*)&w1s[m + j][dtx * 4];
            #pragma unroll
            for (int i = 0; i < 4; ++i) {
                float zv[4];
                *(float4*)&zv[0] = *(const float4*)&zs[dty * 4 + i][m];
                #pragma unroll
                for (int j = 0; j < 4; ++j) {
                    #pragma unroll
                    for (int c = 0; c < 4; ++c)
                        acc[i][c] += zv[j] * wv[j][c];
                }
            }
        }
        float4 b4 = *(const float4*)(bf1 + dtx * 4);
        #pragma unroll
        for (int i = 0; i < 4; ++i) {
            float4 dd;
            dd.x = fmaxf(acc[i][0] + b4.x, 0.f);
            dd.y = fmaxf(acc[i][1] + b4.y, 0.f);
            dd.z = fmaxf(acc[i][2] + b4.z, 0.f);
            dd.w = fmaxf(acc[i][3] + b4.w, 0.f);
            *(float4*)&dsh[dty * 4 + i][dtx * 4] = dd;
        }
    }
    __syncthreads();

    // phase 2: per-wave A-frags in registers (16 nodes/wave, split-bf16)
    bf16x8 ah[2], al[2];
    {
        int row = w * 16 + l16;
        #pragma unroll
        for (int s = 0; s < 2; ++s) {
            int k0 = s * 32 + g * 8;
            float4 f0 = *(float4*)&dsh[row][k0];
            float4 f1 = *(float4*)&dsh[row][k0 + 4];
            float fv[8] = {f0.x, f0.y, f0.z, f0.w, f1.x, f1.y, f1.z, f1.w};
            bf16x8 hv, lv;
            #pragma unroll
            for (int e = 0; e < 8; ++e) {
                unsigned short hh = f2bh(fv[e]);
                hv[e] = (short)hh;
                lv[e] = (short)f2bh(fv[e] - bh2f(hh));
            }
            ah[s] = hv; al[s] = lv;
        }
    }
    __syncthreads();   // dsh dead

    // write prefetched w2 chunk 0 to LDS; prefetch chunk 1
    #pragma unroll
    for (int j = 0; j < 2; ++j) {
        int fi = tid + 256 * j;
        int c = fi >> 3, k8 = (fi & 7) * 8;
        *(uint4*)&w2h[c][k8] = ph[j];
        *(uint4*)&w2l[c][k8] = pl[j];
        ph[j] = *(const uint4*)(w2hg + (size_t)(64 + c) * 64 + k8);
        pl[j] = *(const uint4*)(w2lg + (size_t)(64 + c) * 64 + k8);
    }
    __syncthreads();

    // phase 3: 16 chunks of 64 cols
    for (int ch = 0; ch < 16; ++ch) {
        const int col0 = ch * 64;
        // MFMA from LDS
        f32x4 acc[4] = {};
        #pragma unroll
        for (int nf = 0; nf < 4; ++nf) {
            int c = nf * 16 + l16;
            #pragma unroll
            for (int s = 0; s < 2; ++s) {
                int k0 = s * 32 + g * 8;
                bf16x8 bh = *(const bf16x8*)&w2h[c][k0];
                bf16x8 bl = *(const bf16x8*)&w2l[c][k0];
                acc[nf] = __builtin_amdgcn_mfma_f32_16x16x32_bf16(ah[s], bh, acc[nf], 0, 0, 0);
                acc[nf] = __builtin_amdgcn_mfma_f32_16x16x32_bf16(al[s], bh, acc[nf], 0, 0, 0);
                acc[nf] = __builtin_amdgcn_mfma_f32_16x16x32_bf16(ah[s], bl, acc[nf], 0, 0, 0);
            }
        }
        // bias + relu -> outstage
        #pragma unroll
        for (int nf = 0; nf < 4; ++nf) {
            float b = bf2[col0 + nf * 16 + l16];
            #pragma unroll
            for (int r = 0; r < 4; ++r)
                ost[w * 16 + g * 4 + r][nf * 16 + l16] = fmaxf(acc[nf][r] + b, 0.f);
        }
        __syncthreads();                       // w2 reads done, outstage visible
        // rotate w2 buffers: write next chunk from regs, prefetch chunk+2
        if (ch < 15) {
            #pragma unroll
            for (int j = 0; j < 2; ++j) {
                int fi = tid + 256 * j;
                int c = fi >> 3, k8 = (fi & 7) * 8;
                *(uint4*)&w2h[c][k8] = ph[j];
                *(uint4*)&w2l[c][k8] = pl[j];
                if (ch < 14) {
                    ph[j] = *(const uint4*)(w2hg + (size_t)((ch + 2) * 64 + c) * 64 + k8);
                    pl[j] = *(const uint4*)(w2lg + (size_t)((ch + 2) * 64 + c) * 64 + k8);
                }
            }
        }
        // outstage -> global: 256B-contiguous float4 stores per row
        #pragma unroll
        for (int j = 0; j < 4; ++j) {
            int fi = tid + 256 * j;
            int row = fi >> 4, c4 = (fi & 15) * 4;
            int node = node0 + row;
            if (node < NN) {
                float4 o = *(float4*)&ost[row][c4];
                *(float4*)(out + (size_t)node * 1024 + col0 + c4) = o;
            }
        }
        __syncthreads();                       // w2 writes visible, ost reads done
    }
}

extern "C" void kernel_launch(void* const* d_in, const int* in_sizes, int n_in,
                              void* d_out, int out_size, void* d_ws, size_t ws_size,
                              hipStream_t stream) {
    const float* x   = (const float*)d_in[0];
    const int* ei    = (const int*)d_in[1];
    const float* Wg1 = (const float*)d_in[2];
    const float* bg1 = (const float*)d_in[3];
    const float* Wg2 = (const float*)d_in[4];
    const float* bg2 = (const float*)d_in[5];
    const float* Wf1 = (const float*)d_in[6];
    const float* bf1 = (const float*)d_in[7];
    const float* Wf2 = (const float*)d_in[8];
    const float* bf2 = (const float*)d_in[9];
    float* out = (float*)d_out;
    float* ws  = (float*)d_ws;

    const int* src = ei;
    const int* dst = ei + EE;

    // ws (26 MB): dinv | g2 | z ; Wf2T split tables overlay g2 after gather32.
    float* dinv = ws;
    float* g2   = ws + NN;
    float* z    = ws + NN + 32 * NN;
    unsigned short* wf2h = (unsigned short*)g2;            // 64K u16
    unsigned short* wf2l = wf2h + 64 * 1024;               // 64K u16

    // d_out scratch (all dead before k_decode writes out):
    float* g1 = out;                                       // 64N floats
    float* h  = out + (size_t)64 * NN;                     // 64N floats
    int* bkt  = (int*)(out + (size_t)128 * NN);            // 64N ints (cap 64)
    unsigned int* cursor = (unsigned int*)(bkt + (size_t)64 * NN);  // N (= degree)
    unsigned short* wg1img = (unsigned short*)(cursor + NN);        // 147456 u16

    k_init  <<<(NN + 255) / 256, 256, 0, stream>>>(cursor);
    k_fill  <<<(EE + 255) / 256, 256, 0, stream>>>(src, dst, cursor, bkt);
    k_dinv  <<<(NN + 255) / 256, 256, 0, stream>>>(cursor, dinv);
    k_prepW1<<<256, 256, 0, stream>>>(Wg1, wg1img);
    k_gemm1 <<<(NN + 63) / 64, 256, 0, stream>>>(x, wg1img, dinv, g1);
    k_gather64<<<(NN * 64 + 255) / 256, 256, 0, stream>>>(g1, bkt, cursor, dinv, bg1, h);
    k_layer2<<<(NN + 63) / 64, 256, 0, stream>>>(h, Wg2, dinv, g2);
    k_gather32<<<(NN * 32 + 255) / 256, 256, 0, stream>>>(g2, bkt, cursor, dinv, bg2, z);
    k_prepW2<<<256, 256, 0, stream>>>(Wf2, wf2h, wf2l);
    k_decode<<<(NN + 63) / 64, 256, 0, stream>>>(z, Wf1, bf1, wf2h, wf2l, bf2, out);
}